// Round 10
// baseline (46.291 us; speedup 1.0000x reference)
//
#include <hip/hip_runtime.h>

#define T_LEN 4096
#define H 16
#define N 16
#define D 64
#define NC 64
#define CL (T_LEN / NC)   // 64
#define CH (CL / 2)       // 32-step halves: keeps VGPR pressure at r9 level

// bf16 storage for the chunk-state buffer (L / entry states): halves its
// HBM traffic. Carry arithmetic stays f32; round-to-nearest-even.
static __device__ __forceinline__ unsigned short f2bf(float f) {
    union { float f; unsigned u; } v; v.f = f;
    unsigned r = (v.u + 0x7fffu + ((v.u >> 16) & 1u)) >> 16;
    return (unsigned short)r;
}
static __device__ __forceinline__ float bf2f(unsigned short s) {
    union { unsigned u; float f; } v; v.u = ((unsigned)s) << 16;
    return v.f;
}

// ---------------------------------------------------------------------------
// Phase 1: one wave per (chunk c, head h). Lane d owns the n-column (16 regs).
// B panel staged in LDS pre-scaled by dt; float4 broadcast reads in the scan.
// Writes L[c][h][n][d] (bf16) and P[h][c] (f32).
// ---------------------------------------------------------------------------
__global__ __launch_bounds__(64)
void phase1(const float* __restrict__ x, const float* __restrict__ dt,
            const float* __restrict__ B, const float* __restrict__ mask,
            const float* __restrict__ log_decay,
            unsigned short* __restrict__ Lb, float* __restrict__ Pbuf) {
    const int c = blockIdx.x, h = blockIdx.y;
    const int d = threadIdx.x;
    const float rate = -__expf(log_decay[h]);
    const int t0 = c * CL;

    __shared__ float Bs[CL * N];                 // 4 KB, dt-scaled
    {
        const float4* Bg = (const float4*)B;
        float4* Bsv = (float4*)Bs;
#pragma unroll
        for (int i = 0; i < (CL * N / 4) / 64; ++i) {   // 4 iters
            const int j = i * 64 + d;
            const int row = j >> 2, off = j & 3;
            const float dtv = dt[(t0 + row) * H + h];
            float4 bv = Bg[((t0 + row) * H + h) * (N / 4) + off];
            bv.x *= dtv; bv.y *= dtv; bv.z *= dtv; bv.w *= dtv;
            Bsv[j] = bv;
        }
    }
    __syncthreads();

    float s[N];
#pragma unroll
    for (int n = 0; n < N; ++n) s[n] = 0.f;
    float P = 1.f;

#pragma unroll 1
    for (int half = 0; half < 2; ++half) {
#pragma unroll
        for (int s2 = 0; s2 < CH; ++s2) {
            const int ss = half * CH + s2;
            const int t = t0 + ss;
            const float dtv = dt[t * H + h];          // s_load
            const float mv  = mask[t];                // s_load
            const float a   = (1.f - mv) * __expf(dtv * rate);
            const float xv  = x[(t * H + h) * D + d]; // per-lane coalesced
            P *= a;
            const float4* Br4 = (const float4*)(Bs + ss * N);
#pragma unroll
            for (int q = 0; q < 4; ++q) {             // ds_read_b128 broadcast
                const float4 bv = Br4[q];
                s[4*q+0] = a * s[4*q+0] + bv.x * xv;
                s[4*q+1] = a * s[4*q+1] + bv.y * xv;
                s[4*q+2] = a * s[4*q+2] + bv.z * xv;
                s[4*q+3] = a * s[4*q+3] + bv.w * xv;
            }
        }
    }

    unsigned short* Lp = Lb + ((c * H + h) * N) * D + d;
#pragma unroll
    for (int n = 0; n < N; ++n) Lp[n * D] = f2bf(s[n]);
    if (d == 0) Pbuf[h * NC + c] = P;             // [h][c]
}

// ---------------------------------------------------------------------------
// Phase 2: 16384 threads, one per (h,n,d). Single 64-deep prefetch round.
// h block-uniform -> P reads are s_loads. Overwrites L in place with chunk
// ENTRY states (bf16); writes next_carry (f32).
// ---------------------------------------------------------------------------
__global__ __launch_bounds__(256)
void phase2(const float* __restrict__ initial_carry,
            unsigned short* __restrict__ LE, const float* __restrict__ Pbuf,
            float* __restrict__ next_carry) {
    const int idx = blockIdx.x * 256 + threadIdx.x;  // h*1024 + n*64 + d
    const int h = blockIdx.x >> 2;                   // block-uniform
    float carry = initial_carry[idx];

    float l[NC];
#pragma unroll
    for (int k = 0; k < NC; ++k)
        l[k] = bf2f(LE[k * (H * N * D) + idx]);
#pragma unroll
    for (int k = 0; k < NC; ++k) {
        const float p = Pbuf[h * NC + k];            // s_load
        LE[k * (H * N * D) + idx] = f2bf(carry);     // entry state
        carry = p * carry + l[k];
    }
    next_carry[idx] = carry;
}

// ---------------------------------------------------------------------------
// Phase 3: re-scan each chunk from its (bf16) entry state; fused C-projection
// + skip. B (dt-scaled) and C panels in LDS, float4 broadcast reads.
// Nontemporal output stores (nothing re-reads out).
// ---------------------------------------------------------------------------
__global__ __launch_bounds__(64)
void phase3(const float* __restrict__ x, const float* __restrict__ dt,
            const float* __restrict__ B, const float* __restrict__ C,
            const float* __restrict__ mask, const float* __restrict__ log_decay,
            const float* __restrict__ skip_weight,
            const unsigned short* __restrict__ Eb, float* __restrict__ out) {
    const int c = blockIdx.x, h = blockIdx.y;
    const int d = threadIdx.x;
    const float rate = -__expf(log_decay[h]);
    const int t0 = c * CL;

    __shared__ float Bs[CL * N], Cs[CL * N];         // 8 KB
    {
        const float4* Bg = (const float4*)B;
        const float4* Cg = (const float4*)C;
        float4* Bsv = (float4*)Bs;
        float4* Csv = (float4*)Cs;
#pragma unroll
        for (int i = 0; i < (CL * N / 4) / 64; ++i) {   // 4 iters
            const int j = i * 64 + d;
            const int row = j >> 2, off = j & 3;
            const float dtv = dt[(t0 + row) * H + h];
            float4 bv = Bg[((t0 + row) * H + h) * (N / 4) + off];
            bv.x *= dtv; bv.y *= dtv; bv.z *= dtv; bv.w *= dtv;
            Bsv[j] = bv;
            Csv[j] = Cg[((t0 + row) * H + h) * (N / 4) + off];
        }
    }
    __syncthreads();

    float s[N];
    const unsigned short* Ep = Eb + ((c * H + h) * N) * D + d;
#pragma unroll
    for (int n = 0; n < N; ++n) s[n] = bf2f(Ep[n * D]);

    const float sw = skip_weight[h * D + d];
#pragma unroll 1
    for (int half = 0; half < 2; ++half) {
#pragma unroll
        for (int s2 = 0; s2 < CH; ++s2) {
            const int ss = half * CH + s2;
            const int t = t0 + ss;
            const float dtv = dt[t * H + h];
            const float mv  = mask[t];
            const float a   = (1.f - mv) * __expf(dtv * rate);
            const float xv  = x[(t * H + h) * D + d];
            float acc = sw * xv;
            const float4* Br4 = (const float4*)(Bs + ss * N);
            const float4* Cr4 = (const float4*)(Cs + ss * N);
#pragma unroll
            for (int q = 0; q < 4; ++q) {
                const float4 bv = Br4[q];
                const float4 cv = Cr4[q];
                s[4*q+0] = a * s[4*q+0] + bv.x * xv;  acc += cv.x * s[4*q+0];
                s[4*q+1] = a * s[4*q+1] + bv.y * xv;  acc += cv.y * s[4*q+1];
                s[4*q+2] = a * s[4*q+2] + bv.z * xv;  acc += cv.z * s[4*q+2];
                s[4*q+3] = a * s[4*q+3] + bv.w * xv;  acc += cv.w * s[4*q+3];
            }
            __builtin_nontemporal_store(acc, &out[(t * H + h) * D + d]);
        }
    }
}

extern "C" void kernel_launch(void* const* d_in, const int* in_sizes, int n_in,
                              void* d_out, int out_size, void* d_ws, size_t ws_size,
                              hipStream_t stream) {
    const float* x    = (const float*)d_in[0];
    const float* dt   = (const float*)d_in[1];
    const float* B    = (const float*)d_in[2];
    const float* C    = (const float*)d_in[3];
    const float* mask = (const float*)d_in[4];
    const float* ic   = (const float*)d_in[5];
    const float* ld   = (const float*)d_in[6];
    const float* sw   = (const float*)d_in[7];
    float* out = (float*)d_out;

    // ws layout: [Pbuf: H*NC f32 = 4 KB][Lb: NC*H*N*D bf16 = 2.1 MB]
    float* Pbuf = (float*)d_ws;
    unsigned short* Lb = (unsigned short*)((char*)d_ws + 4096);

    dim3 grid(NC, H), block(64);
    phase1<<<grid, block, 0, stream>>>(x, dt, B, mask, ld, Lb, Pbuf);
    phase2<<<dim3(H * N * D / 256), dim3(256), 0, stream>>>(ic, Lb, Pbuf, out);
    phase3<<<grid, block, 0, stream>>>(x, dt, B, C, mask, ld, sw, Lb, out + H * N * D);
}

// Round 11
// 38.292 us; speedup vs baseline: 1.2089x; 1.2089x over previous
//
#include <hip/hip_runtime.h>

#define T_LEN 4096
#define H 16
#define N 16
#define D 64
#define NC 256
#define CL (T_LEN / NC)   // 16

// bf16 storage for the chunk-state buffer (L / entry states): halves its
// HBM traffic vs f32. Carry arithmetic stays f32; round-to-nearest-even.
static __device__ __forceinline__ unsigned short f2bf(float f) {
    union { float f; unsigned u; } v; v.f = f;
    unsigned r = (v.u + 0x7fffu + ((v.u >> 16) & 1u)) >> 16;
    return (unsigned short)r;
}
static __device__ __forceinline__ float bf2f(unsigned short s) {
    union { unsigned u; float f; } v; v.u = ((unsigned)s) << 16;
    return v.f;
}

// ---------------------------------------------------------------------------
// Phase 1: one wave per (chunk c, head h) -- 4096 waves = 16/CU (2x r9's
// parallelism, half the serial chain). Lane d owns the n-column (16 regs).
// B panel staged in LDS pre-scaled by dt; float4 broadcast reads.
// Writes L[c][h][n][d] (bf16) and P[h][c] (f32).
// ---------------------------------------------------------------------------
__global__ __launch_bounds__(64)
void phase1(const float* __restrict__ x, const float* __restrict__ dt,
            const float* __restrict__ B, const float* __restrict__ mask,
            const float* __restrict__ log_decay,
            unsigned short* __restrict__ Lb, float* __restrict__ Pbuf) {
    const int c = blockIdx.x, h = blockIdx.y;
    const int d = threadIdx.x;
    const float rate = -__expf(log_decay[h]);
    const int t0 = c * CL;

    __shared__ float Bs[CL * N];                 // 1 KB, dt-scaled
    {
        const float4* Bg = (const float4*)B;
        float4* Bsv = (float4*)Bs;
        const int j = d;                         // CL*N/4 = 64 -> 1 per lane
        const int row = j >> 2, off = j & 3;
        const float dtv = dt[(t0 + row) * H + h];
        float4 bv = Bg[((t0 + row) * H + h) * (N / 4) + off];
        bv.x *= dtv; bv.y *= dtv; bv.z *= dtv; bv.w *= dtv;
        Bsv[j] = bv;
    }
    __syncthreads();

    float s[N];
#pragma unroll
    for (int n = 0; n < N; ++n) s[n] = 0.f;
    float P = 1.f;

#pragma unroll
    for (int ss = 0; ss < CL; ++ss) {
        const int t = t0 + ss;
        const float dtv = dt[t * H + h];          // s_load
        const float mv  = mask[t];                // s_load
        const float a   = (1.f - mv) * __expf(dtv * rate);
        const float xv  = x[(t * H + h) * D + d]; // per-lane coalesced
        P *= a;
        const float4* Br4 = (const float4*)(Bs + ss * N);
#pragma unroll
        for (int q = 0; q < 4; ++q) {             // ds_read_b128 broadcast
            const float4 bv = Br4[q];
            s[4*q+0] = a * s[4*q+0] + bv.x * xv;
            s[4*q+1] = a * s[4*q+1] + bv.y * xv;
            s[4*q+2] = a * s[4*q+2] + bv.z * xv;
            s[4*q+3] = a * s[4*q+3] + bv.w * xv;
        }
    }

    unsigned short* Lp = Lb + ((c * H + h) * N) * D + d;
#pragma unroll
    for (int n = 0; n < N; ++n) Lp[n * D] = f2bf(s[n]);
    if (d == 0) Pbuf[h * NC + c] = P;             // [h][c]
}

// ---------------------------------------------------------------------------
// Phase 2: 16384 threads, one per (h,n,d). 4 rounds of 64-deep prefetch.
// h block-uniform -> P reads are s_loads. Overwrites L in place with chunk
// ENTRY states (bf16); writes next_carry (f32).
// ---------------------------------------------------------------------------
__global__ __launch_bounds__(256)
void phase2(const float* __restrict__ initial_carry,
            unsigned short* __restrict__ LE, const float* __restrict__ Pbuf,
            float* __restrict__ next_carry) {
    const int idx = blockIdx.x * 256 + threadIdx.x;  // h*1024 + n*64 + d
    const int h = blockIdx.x >> 2;                   // block-uniform
    float carry = initial_carry[idx];

#pragma unroll
    for (int r = 0; r < NC / 64; ++r) {              // 4 rounds
        float l[64];
#pragma unroll
        for (int k = 0; k < 64; ++k)
            l[k] = bf2f(LE[(r * 64 + k) * (H * N * D) + idx]);
#pragma unroll
        for (int k = 0; k < 64; ++k) {
            const float p = Pbuf[h * NC + r * 64 + k];   // s_load
            LE[(r * 64 + k) * (H * N * D) + idx] = f2bf(carry);  // entry
            carry = p * carry + l[k];
        }
    }
    next_carry[idx] = carry;
}

// ---------------------------------------------------------------------------
// Phase 3: re-scan each chunk from its (bf16) entry state; fused
// C-projection + skip. B (dt-scaled) and C panels in LDS, float4 broadcast
// reads. Nontemporal output stores.
// ---------------------------------------------------------------------------
__global__ __launch_bounds__(64)
void phase3(const float* __restrict__ x, const float* __restrict__ dt,
            const float* __restrict__ B, const float* __restrict__ C,
            const float* __restrict__ mask, const float* __restrict__ log_decay,
            const float* __restrict__ skip_weight,
            const unsigned short* __restrict__ Eb, float* __restrict__ out) {
    const int c = blockIdx.x, h = blockIdx.y;
    const int d = threadIdx.x;
    const float rate = -__expf(log_decay[h]);
    const int t0 = c * CL;

    __shared__ float Bs[CL * N], Cs[CL * N];         // 2 KB
    {
        const float4* Bg = (const float4*)B;
        const float4* Cg = (const float4*)C;
        float4* Bsv = (float4*)Bs;
        float4* Csv = (float4*)Cs;
        const int j = d;                             // 1 per lane
        const int row = j >> 2, off = j & 3;
        const float dtv = dt[(t0 + row) * H + h];
        float4 bv = Bg[((t0 + row) * H + h) * (N / 4) + off];
        bv.x *= dtv; bv.y *= dtv; bv.z *= dtv; bv.w *= dtv;
        Bsv[j] = bv;
        Csv[j] = Cg[((t0 + row) * H + h) * (N / 4) + off];
    }
    __syncthreads();

    float s[N];
    const unsigned short* Ep = Eb + ((c * H + h) * N) * D + d;
#pragma unroll
    for (int n = 0; n < N; ++n) s[n] = bf2f(Ep[n * D]);

    const float sw = skip_weight[h * D + d];
#pragma unroll
    for (int ss = 0; ss < CL; ++ss) {
        const int t = t0 + ss;
        const float dtv = dt[t * H + h];
        const float mv  = mask[t];
        const float a   = (1.f - mv) * __expf(dtv * rate);
        const float xv  = x[(t * H + h) * D + d];
        float acc = sw * xv;
        const float4* Br4 = (const float4*)(Bs + ss * N);
        const float4* Cr4 = (const float4*)(Cs + ss * N);
#pragma unroll
        for (int q = 0; q < 4; ++q) {
            const float4 bv = Br4[q];
            const float4 cv = Cr4[q];
            s[4*q+0] = a * s[4*q+0] + bv.x * xv;  acc += cv.x * s[4*q+0];
            s[4*q+1] = a * s[4*q+1] + bv.y * xv;  acc += cv.y * s[4*q+1];
            s[4*q+2] = a * s[4*q+2] + bv.z * xv;  acc += cv.z * s[4*q+2];
            s[4*q+3] = a * s[4*q+3] + bv.w * xv;  acc += cv.w * s[4*q+3];
        }
        __builtin_nontemporal_store(acc, &out[(t * H + h) * D + d]);
    }
}

extern "C" void kernel_launch(void* const* d_in, const int* in_sizes, int n_in,
                              void* d_out, int out_size, void* d_ws, size_t ws_size,
                              hipStream_t stream) {
    const float* x    = (const float*)d_in[0];
    const float* dt   = (const float*)d_in[1];
    const float* B    = (const float*)d_in[2];
    const float* C    = (const float*)d_in[3];
    const float* mask = (const float*)d_in[4];
    const float* ic   = (const float*)d_in[5];
    const float* ld   = (const float*)d_in[6];
    const float* sw   = (const float*)d_in[7];
    float* out = (float*)d_out;

    // ws layout: [Pbuf: H*NC f32 = 16 KB][Lb: NC*H*N*D bf16 = 8.4 MB]
    float* Pbuf = (float*)d_ws;
    unsigned short* Lb = (unsigned short*)((char*)d_ws + 16384);

    dim3 grid(NC, H), block(64);
    phase1<<<grid, block, 0, stream>>>(x, dt, B, mask, ld, Lb, Pbuf);
    phase2<<<dim3(H * N * D / 256), dim3(256), 0, stream>>>(ic, Lb, Pbuf, out);
    phase3<<<grid, block, 0, stream>>>(x, dt, B, C, mask, ld, sw, Lb, out + H * N * D);
}